// Round 3
// baseline (1534.042 us; speedup 1.0000x reference)
//
#include <hip/hip_runtime.h>
#include <stdint.h>

typedef unsigned short u16;
typedef __bf16 bf16x8 __attribute__((ext_vector_type(8)));
typedef float f32x4 __attribute__((ext_vector_type(4)));

#define N_TOK 16384
#define DIM   1024
#define NEXP  8
#define HID   4096
#define MT256 136           // max row-tiles: 32768/256 + 8 pad tiles
#define PADROWS 34816       // MT256*256

__device__ __forceinline__ u16 f2bf(float f) {
  uint32_t u = __builtin_bit_cast(uint32_t, f);
  u += 0x7fffu + ((u >> 16) & 1u);   // RNE for finite values
  return (u16)(u >> 16);
}

__device__ __forceinline__ void gload16(const void* g, void* l) {
  __builtin_amdgcn_global_load_lds(
      (const __attribute__((address_space(1))) uint32_t*)g,
      (__attribute__((address_space(3))) uint32_t*)l, 16, 0, 0);
}

// ---------------- init / cast / transpose ----------------

__global__ void k_zero(int* counts) {
  if (threadIdx.x < NEXP) counts[threadIdx.x] = 0;
}

__global__ void k_cast_x(const float* __restrict__ s, u16* __restrict__ d) {
  size_t i = ((size_t)blockIdx.x * 256 + threadIdx.x) * 4;
  float4 v = *(const float4*)(s + i);
  u16* o = d + i;
  o[0] = f2bf(v.x); o[1] = f2bf(v.y); o[2] = f2bf(v.z); o[3] = f2bf(v.w);
}

// src: [E][R][C] f32  ->  dst: [E][C][R] bf16
__global__ void k_tcast(const float* __restrict__ src, u16* __restrict__ dst,
                        int R, int C) {
  __shared__ float tile[32][33];
  int nc = C >> 5, nr = R >> 5;
  int t = blockIdx.x;
  int cb = t % nc; t /= nc;
  int rb = t % nr; int ee = t / nr;
  const float* s0 = src + ((size_t)ee * R + (size_t)rb * 32) * C + cb * 32;
  int tx = threadIdx.x & 31, ty = threadIdx.x >> 5;
#pragma unroll
  for (int i = 0; i < 4; ++i)
    tile[ty + i * 8][tx] = s0[(size_t)(ty + i * 8) * C + tx];
  __syncthreads();
  u16* d0 = dst + ((size_t)ee * C + (size_t)cb * 32) * R + rb * 32;
#pragma unroll
  for (int i = 0; i < 4; ++i)
    d0[(size_t)(ty + i * 8) * R + tx] = f2bf(tile[tx][ty + i * 8]);
}

// ---------------- gate: logits -> top2 -> gates ----------------

__global__ __launch_bounds__(256) void k_gate(
    const float* __restrict__ x, const float* __restrict__ Wg,
    const float* __restrict__ bg, int* __restrict__ tok_e,
    float* __restrict__ tok_g, int* __restrict__ counts,
    float* __restrict__ blocksums) {
  __shared__ float wg_s[NEXP * DIM];
  __shared__ float s4[4];
  for (int i = threadIdx.x; i < NEXP * DIM; i += 256) {
    int k = i >> 3, e = i & 7;
    wg_s[e * DIM + k] = Wg[i];
  }
  __syncthreads();
  int lane = threadIdx.x & 63, wv = threadIdx.x >> 6;
  int n = blockIdx.x * 4 + wv;
  const float* xr = x + (size_t)n * DIM;
  float xv[16];
#pragma unroll
  for (int i = 0; i < 16; ++i) xv[i] = xr[lane + 64 * i];
  float acc[8];
#pragma unroll
  for (int e = 0; e < 8; ++e) {
    const float* w = wg_s + e * DIM + lane;
    float a = 0.f;
#pragma unroll
    for (int i = 0; i < 16; ++i) a += xv[i] * w[64 * i];
    acc[e] = a;
  }
#pragma unroll
  for (int e = 0; e < 8; ++e)
#pragma unroll
    for (int off = 32; off > 0; off >>= 1)
      acc[e] += __shfl_xor(acc[e], off);

  if (lane == 0) {
    float l0 = -1e30f, l1 = -1e30f; int e0 = 0, e1 = 0;
#pragma unroll
    for (int e = 0; e < 8; ++e) {
      float v = acc[e] + bg[e];
      if (v > l0) { l1 = l0; e1 = e0; l0 = v; e0 = e; }
      else if (v > l1) { l1 = v; e1 = e; }
    }
    float g0 = 1.f / (1.f + expf(l1 - l0));
    float g1 = 1.f - g0;
    tok_e[2 * n] = e0; tok_e[2 * n + 1] = e1;
    tok_g[2 * n] = g0; tok_g[2 * n + 1] = g1;
    atomicAdd(&counts[e0], 1);
    atomicAdd(&counts[e1], 1);
    s4[wv] = g0;
  }
  __syncthreads();
  if (threadIdx.x == 0) blocksums[blockIdx.x] = s4[0] + s4[1] + s4[2] + s4[3];
}

// ---------------- routing setup (1 block), 256-row tile padding ----------------

__global__ __launch_bounds__(256) void k_setup(
    const int* __restrict__ counts, const float* __restrict__ blocksums,
    int* __restrict__ padded_off, int* __restrict__ cursor,
    int* __restrict__ row2tok, float* __restrict__ row2gate,
    float* __restrict__ aux_out) {
  __shared__ float red[256];
  __shared__ int off_s[9];
  float s = 0.f;
  for (int i = threadIdx.x; i < 4096; i += 256) s += blocksums[i];
  red[threadIdx.x] = s;
  __syncthreads();
  for (int st = 128; st > 0; st >>= 1) {
    if (threadIdx.x < st) red[threadIdx.x] += red[threadIdx.x + st];
    __syncthreads();
  }
  if (threadIdx.x == 0) {
    int off = 0, nact = 0;
    for (int e = 0; e < 8; ++e) {
      off_s[e] = off;
      int c = counts[e];
      if (c > 0) nact++;
      off += ((c + 255) >> 8) << 8;   // pad each expert to 256-row tiles
      cursor[e] = 0;
    }
    off_s[8] = off;
    for (int e = 0; e <= 8; ++e) padded_off[e] = off_s[e];
    float m = red[0] / (float)N_TOK;
    *aux_out = (float)nact * m * m;
  }
  __syncthreads();
  for (int idx = threadIdx.x; idx < NEXP * 256; idx += 256) {
    int e = idx >> 8, i = idx & 255;
    int slot = off_s[e] + counts[e] + i;
    if (slot < off_s[e + 1]) { row2tok[slot] = 0; row2gate[slot] = 0.f; }
  }
}

__global__ void k_scatter(const int* __restrict__ tok_e,
                          const float* __restrict__ tok_g,
                          const int* __restrict__ padded_off,
                          int* __restrict__ cursor, int* __restrict__ row2tok,
                          float* __restrict__ row2gate) {
  int n = blockIdx.x * 256 + threadIdx.x;
#pragma unroll
  for (int k = 0; k < 2; ++k) {
    int e = tok_e[2 * n + k];
    int pos = atomicAdd(&cursor[e], 1);
    int slot = padded_off[e] + pos;
    row2tok[slot] = n;
    row2gate[slot] = tok_g[2 * n + k];
  }
}

// ---------------- grouped GEMM, 256x256 tile, BK=64 (2x 32-k halves), ------
// 8 waves (2M x 4N), 8-phase schedule with counted vmcnt(6), chunk-XOR LDS
// swizzle (pre-swizzled global source + swizzled ds_read), setprio on MFMA.
// LDS: A,B each 2 tiles x 2 k-halves x 256 rows x 32 k bf16 = 64 KB -> 128 KB.
//
// Stage schedule (phase -> slot <- global k), derived so every read's
// producer stage is >=5 phases old and every overwritten slot was last read
// >=1 barrier earlier; vmcnt(6) before the barrier at ph4/ph8 guarantees all
// waves' stages <= (waitphase-3) have landed before dependent reads:
//  ph1: B1k1 read(t0,k0,ihalf0,+B) | stage A,t1,k1 <- k+96
//  ph2:      read(t0,k0,ihalf1   ) | stage B,t0,k0 <- k+128
//  ph3:      read(t0,k1,ihalf0,+B) | stage A,t0,k0 <- k+128
//  ph4:      read(t0,k1,ihalf1   ) | stage B,t0,k1 <- k+160 | vmcnt(6)
//  ph5:      read(t1,k0,ihalf0,+B) | stage A,t0,k1 <- k+160
//  ph6:      read(t1,k0,ihalf1   ) | stage B,t1,k0 <- k+192
//  ph7:      read(t1,k1,ihalf0,+B) | stage A,t1,k0 <- k+192
//  ph8:      read(t1,k1,ihalf1   ) | stage B,t1,k1 <- k+224 | vmcnt(6)

template <int KDIM, int MODE>   // MODE 0: gemm1 (h=relu(xW1+b1)), 1: gemm2
__global__ __launch_bounds__(512, 2) void k_gemm(
    const u16* __restrict__ Asrc, const u16* __restrict__ Wt,
    const float* __restrict__ bias, const int* __restrict__ row2tok,
    const float* __restrict__ row2gate, const int* __restrict__ padded_off,
    void* __restrict__ Out) {
  __shared__ u16 ldsA[32768];
  __shared__ u16 ldsB[32768];
  constexpr int NDIM = MODE ? DIM : HID;
  int row0 = blockIdx.y * 256;
  if (row0 >= padded_off[8]) return;
  int e = 0;
  while (row0 >= padded_off[e + 1]) ++e;
  int n0 = blockIdx.x * 256;
  int tid = threadIdx.x, lane = tid & 63, wv = tid >> 6;
  int wm = wv >> 2, wn = wv & 3;
  int fr = lane & 15, fq = lane >> 4;
  // swizzled ds_read offset (u16 elems within a 16KB k-half)
  int ao = (fr * 32 + fq * 8) ^ (((fr >> 1) & 3) * 8);
  // staging: linear LDS dest chunk q holds logical (row=q>>2, slot=(q&3)^((row>>1)&3))
  int q0 = wv * 64 + lane, q1 = q0 + 512;
  int r0 = q0 >> 2, r1 = q1 >> 2;
  int s0 = (q0 & 3) ^ ((r0 >> 1) & 3), s1 = (q1 & 3) ^ ((r1 >> 1) & 3);
  const u16 *srcA0, *srcA1;
  if (MODE == 0) {
    srcA0 = Asrc + (size_t)row2tok[row0 + r0] * KDIM + s0 * 8;
    srcA1 = Asrc + (size_t)row2tok[row0 + r1] * KDIM + s1 * 8;
  } else {
    srcA0 = Asrc + (size_t)(row0 + r0) * KDIM + s0 * 8;
    srcA1 = Asrc + (size_t)(row0 + r1) * KDIM + s1 * 8;
  }
  const u16* wp = Wt + (size_t)e * (HID * DIM);
  const u16* srcB0 = wp + (size_t)(n0 + r0) * KDIM + s0 * 8;
  const u16* srcB1 = wp + (size_t)(n0 + r1) * KDIM + s1 * 8;

  f32x4 acc[8][4];
#pragma unroll
  for (int i = 0; i < 8; ++i)
#pragma unroll
    for (int j = 0; j < 4; ++j) acc[i][j] = (f32x4){0.f, 0.f, 0.f, 0.f};
  bf16x8 av[4], bv[4];

#define ST(OP, T, KK, KOFF)                                             \
  do {                                                                  \
    int kg = (KOFF); if (kg >= KDIM) kg -= KDIM;                        \
    u16* sd = ((OP) ? ldsB : ldsA) + (T) * 16384 + (KK) * 8192 + wv * 512; \
    gload16(((OP) ? srcB0 : srcA0) + kg, sd);                           \
    gload16(((OP) ? srcB1 : srcA1) + kg, sd + 4096);                    \
  } while (0)

#define CMP(T, KK, IH, LB)                                              \
  do {                                                                  \
    if (LB) {                                                           \
      const u16* Bh = ldsB + (T) * 16384 + (KK) * 8192 + wn * 2048 + ao; \
      bv[0] = *(const bf16x8*)(Bh);        bv[1] = *(const bf16x8*)(Bh + 512); \
      bv[2] = *(const bf16x8*)(Bh + 1024); bv[3] = *(const bf16x8*)(Bh + 1536); \
    }                                                                   \
    const u16* Ah = ldsA + (T) * 16384 + (KK) * 8192 + wm * 4096 + (IH) * 2048 + ao; \
    av[0] = *(const bf16x8*)(Ah);        av[1] = *(const bf16x8*)(Ah + 512); \
    av[2] = *(const bf16x8*)(Ah + 1024); av[3] = *(const bf16x8*)(Ah + 1536); \
  } while (0)

#define PHASE(T, KK, IH, LB, SOP, STILE, SKK, SKOFF, VM)                \
  do {                                                                  \
    CMP(T, KK, IH, LB);                                                 \
    ST(SOP, STILE, SKK, SKOFF);                                         \
    if (VM) asm volatile("s_waitcnt vmcnt(6)");                         \
    asm volatile("s_barrier" ::: "memory");                             \
    asm volatile("s_waitcnt lgkmcnt(0)" ::: "memory");                  \
    __builtin_amdgcn_sched_barrier(0);                                  \
    __builtin_amdgcn_s_setprio(1);                                      \
    _Pragma("unroll") for (int ii = 0; ii < 4; ++ii)                    \
    _Pragma("unroll") for (int j = 0; j < 4; ++j)                       \
      acc[(IH) * 4 + ii][j] = __builtin_amdgcn_mfma_f32_16x16x32_bf16(  \
          av[ii], bv[j], acc[(IH) * 4 + ii][j], 0, 0, 0);               \
    __builtin_amdgcn_s_setprio(0);                                      \
    asm volatile("s_barrier" ::: "memory");                             \
  } while (0)

  // prologue: t0 complete + t1 {Bk0, Ak0, Bk1}; leave last 3 halves in flight
  ST(1, 0, 0, 0);  ST(0, 0, 0, 0);  ST(1, 0, 1, 32); ST(0, 0, 1, 32);
  ST(1, 1, 0, 64); ST(0, 1, 0, 64); ST(1, 1, 1, 96);
  asm volatile("s_waitcnt vmcnt(6)");
  asm volatile("s_barrier" ::: "memory");

  for (int kt = 0; kt < KDIM / 128; ++kt) {
    int k0 = kt * 128;
    PHASE(0, 0, 0, 1, 0, 1, 1, k0 + 96,  0);
    PHASE(0, 0, 1, 0, 1, 0, 0, k0 + 128, 0);
    PHASE(0, 1, 0, 1, 0, 0, 0, k0 + 128, 0);
    PHASE(0, 1, 1, 0, 1, 0, 1, k0 + 160, 1);
    PHASE(1, 0, 0, 1, 0, 0, 1, k0 + 160, 0);
    PHASE(1, 0, 1, 0, 1, 1, 0, k0 + 192, 0);
    PHASE(1, 1, 0, 1, 0, 1, 0, k0 + 192, 0);
    PHASE(1, 1, 1, 0, 1, 1, 1, k0 + 224, 1);
  }
#undef PHASE
#undef CMP
#undef ST

  float bv4[4];
#pragma unroll
  for (int j = 0; j < 4; ++j)
    bv4[j] = bias[e * NDIM + n0 + wn * 64 + j * 16 + fr];

  if (MODE == 0) {
    u16* hp = (u16*)Out;
#pragma unroll
    for (int i = 0; i < 8; ++i)
#pragma unroll
      for (int jj = 0; jj < 4; ++jj) {
        int grow = row0 + wm * 128 + i * 16 + fq * 4 + jj;
        u16* hr = hp + (size_t)grow * HID + n0 + wn * 64 + fr;
#pragma unroll
        for (int j = 0; j < 4; ++j) {
          float v = acc[i][j][jj] + bv4[j];
          hr[j * 16] = f2bf(v > 0.f ? v : 0.f);
        }
      }
  } else {
    float* op = (float*)Out;
#pragma unroll
    for (int i = 0; i < 8; ++i)
#pragma unroll
      for (int jj = 0; jj < 4; ++jj) {
        int grow = row0 + wm * 128 + i * 16 + fq * 4 + jj;
        int tok = row2tok[grow];
        float g = row2gate[grow];
        float* orow = op + (size_t)tok * DIM + n0 + wn * 64 + fr;
#pragma unroll
        for (int j = 0; j < 4; ++j)
          atomicAdd(orow + j * 16, g * (acc[i][j][jj] + bv4[j]));
      }
  }
}

// ---------------- launch ----------------

extern "C" void kernel_launch(void* const* d_in, const int* in_sizes, int n_in,
                              void* d_out, int out_size, void* d_ws,
                              size_t ws_size, hipStream_t stream) {
  const float* x  = (const float*)d_in[0];
  const float* Wg = (const float*)d_in[1];
  const float* bg = (const float*)d_in[2];
  const float* W1 = (const float*)d_in[3];
  const float* b1 = (const float*)d_in[4];
  const float* W2 = (const float*)d_in[5];
  const float* b2 = (const float*)d_in[6];
  float* out = (float*)d_out;

  // workspace layout (bytes); total ~369 MiB. wT is shared: W1^T for gemm1,
  // then overwritten with W2^T (stream-serialized) for gemm2.
  char* w = (char*)d_ws;
  u16* xb          = (u16*)(w);                  //  33,554,432
  u16* wT          = (u16*)(w + 33554432);       //  67,108,864
  u16* h           = (u16*)(w + 100663296);      // 285,212,672 [PADROWS][H]
  int* tok_e       = (int*)(w + 385875968);      // 131,072
  float* tok_g     = (float*)(w + 386007040);    // 131,072
  int* counts      = (int*)(w + 386138112);
  int* cursor      = (int*)(w + 386138368);
  int* padded_off  = (int*)(w + 386138624);
  int* row2tok     = (int*)(w + 386138880);      // 139,264
  float* row2gate  = (float*)(w + 386278144);    // 139,264
  float* blocksums = (float*)(w + 386417408);    // 16,384

  k_zero<<<1, 64, 0, stream>>>(counts);
  k_cast_x<<<16384, 256, 0, stream>>>(x, xb);
  k_gate<<<4096, 256, 0, stream>>>(x, Wg, bg, tok_e, tok_g, counts, blocksums);
  hipMemsetAsync(d_out, 0, (size_t)N_TOK * DIM * sizeof(float), stream);
  k_setup<<<1, 256, 0, stream>>>(counts, blocksums, padded_off, cursor, row2tok,
                                 row2gate, out + (size_t)N_TOK * DIM);
  k_scatter<<<64, 256, 0, stream>>>(tok_e, tok_g, padded_off, cursor, row2tok,
                                    row2gate);
  k_tcast<<<32768, 256, 0, stream>>>(W1, wT, DIM, HID);
  k_gemm<DIM, 0><<<dim3(HID / 256, MT256), 512, 0, stream>>>(
      xb, wT, b1, row2tok, row2gate, padded_off, h);
  k_tcast<<<32768, 256, 0, stream>>>(W2, wT, HID, DIM);
  k_gemm<HID, 1><<<dim3(DIM / 256, MT256), 512, 0, stream>>>(
      h, wT, b2, row2tok, row2gate, padded_off, out);
}